// Round 11
// baseline (179.131 us; speedup 1.0000x reference)
//
#include <hip/hip_runtime.h>
#include <hip/hip_bf16.h>

// MHA forward, MI355X gfx950. bf16 MFMA internal compute, fp32 accumulate.
// Shapes: B=2, T=2048, C=1024, H=16, dk=64.

using short8 = __attribute__((ext_vector_type(8))) short;  // 8 bf16 (4 VGPRs)
using f32x4  = __attribute__((ext_vector_type(4))) float;  // 4 fp32 acc
using fp16x2 = __attribute__((ext_vector_type(2))) __fp16; // cvt_pkrtz result
using half4  = __attribute__((ext_vector_type(4))) _Float16;
using half8  = __attribute__((ext_vector_type(8))) _Float16;

#define SCALE_LOG2E 0.18033688011112042f   // 0.125 * log2(e), folded into Wq

__device__ __forceinline__ unsigned short f2bf(float f) {
    union { float f; unsigned u; } v; v.f = f;
    unsigned r = v.u + 0x7fffu + ((v.u >> 16) & 1u);   // RNE
    return (unsigned short)(r >> 16);
}

// async global->LDS, 16B per lane (CK-style uintptr cast)
__device__ __forceinline__ void gld16(const unsigned short* gp, unsigned short* lp) {
    __builtin_amdgcn_global_load_lds(
        (const __attribute__((address_space(1))) void*)(gp),
        (__attribute__((address_space(3))) void*)(unsigned int)(unsigned long long)(lp),
        16, 0, 0);
}

// ---------------- prep: fp32 -> bf16 elementwise (x, Wo) ----------------
__global__ void cvt_bf16(const float* __restrict__ in,
                         unsigned short* __restrict__ out, int n4) {
    int i = blockIdx.x * blockDim.x + threadIdx.x;
    if (i >= n4) return;
    float4 v = ((const float4*)in)[i];
    ushort4 o;
    o.x = f2bf(v.x); o.y = f2bf(v.y); o.z = f2bf(v.z); o.w = f2bf(v.w);
    ((ushort4*)out)[i] = o;
}

// ------- prep: Wq/Wk/Wv [16][1024][64] fp32 -> Wt [48][64][1024] bf16 -------
// Wq rows are pre-scaled by 0.125*log2(e) so attn can use exp2 directly.
__global__ void transpose_w(const float* __restrict__ Wq,
                            const float* __restrict__ Wk,
                            const float* __restrict__ Wv,
                            unsigned short* __restrict__ out) {
    __shared__ float tile[64][65];            // +1 pad: no bank conflicts
    int b = blockIdx.x;                        // 0..767
    int cchunk = b & 15;                       // c0 = cchunk*64
    int h = (b >> 4) & 15;
    int s = b >> 8;                            // 0=q 1=k 2=v
    const float* W = (s == 0) ? Wq : ((s == 1) ? Wk : Wv);
    float sc = (s == 0) ? SCALE_LOG2E : 1.0f;
    const float* src = W + (h * 1024 + cchunk * 64) * 64;   // [64 c][64 k]
    int t = threadIdx.x;
    #pragma unroll
    for (int it = 0; it < 4; ++it) {
        int idx = (it * 256 + t) * 4;          // 0..4095 step 4
        int cc = idx >> 6, kk = idx & 63;
        float4 v = *(const float4*)(src + idx);
        tile[cc][kk + 0] = v.x; tile[cc][kk + 1] = v.y;
        tile[cc][kk + 2] = v.z; tile[cc][kk + 3] = v.w;
    }
    __syncthreads();
    unsigned short* dst = out + (size_t)((s * 16 + h) * 64) * 1024 + cchunk * 64;
    #pragma unroll
    for (int it = 0; it < 16; ++it) {
        int idx = it * 256 + t;                // 0..4095
        int kk = idx >> 6, cc = idx & 63;
        dst[kk * 1024 + cc] = f2bf(tile[cc][kk] * sc);
    }
}

// ---------------- QKV projection GEMM ----------------
// 128x64 tile (BK=32, swizzled), grid (32,48) = 1536 blocks = 6 blocks/CU
// (round-10 128x128 grid was 3 blocks/CU -> Occupancy 15%, the limiter).
// 4 waves, each 64(M)x32(N): acc[4][2]. launch_bounds(256,5) caps VGPR ~102.
// Writes Q in [bh][t][64] bf16; K in kfrag[bh][kv16][h][lane][8] bf16;
// V in vfrag[bh][kv32][nb][lane][8] f16 (attn's exact MFMA operand layouts).
__global__ __launch_bounds__(256, 5) void qkv_gemm(
        const unsigned short* __restrict__ xb,
        const unsigned short* __restrict__ Wt,
        unsigned short* __restrict__ qB,
        unsigned short* __restrict__ kfrag,
        _Float16* __restrict__ vfrag) {
    __shared__ unsigned short Als[128 * 32];
    __shared__ unsigned short Bls[64 * 32];
    int wave = threadIdx.x >> 6;
    int lane = threadIdx.x & 63;
    int col  = lane & 15;
    int quad = lane >> 4;
    int m_off = (wave & 1) * 64;
    int n_off = (wave >> 1) * 32;
    int ldr = lane >> 2;
    int ldc = ((lane & 3) ^ ((lane >> 3) & 3)) * 8;
    int swq = (quad ^ ((col >> 1) & 3)) * 8;
    int m0 = blockIdx.x * 128;
    int n0 = blockIdx.y * 64;
    f32x4 acc[4][2] = {};
    for (int k0 = 0; k0 < 1024; k0 += 32) {
        __syncthreads();
        #pragma unroll
        for (int j = 0; j < 2; ++j) {
            int row = wave * 32 + j * 16;
            gld16(xb + (size_t)(m0 + row + ldr) * 1024 + k0 + ldc, Als + row * 32);
        }
        {
            int row = wave * 16;
            gld16(Wt + (size_t)(n0 + row + ldr) * 1024 + k0 + ldc, Bls + row * 32);
        }
        __syncthreads();
        short8 af[4], bf[2];
        #pragma unroll
        for (int i = 0; i < 4; ++i)
            af[i] = *(const short8*)(Als + (m_off + i * 16 + col) * 32 + swq);
        #pragma unroll
        for (int i = 0; i < 2; ++i)
            bf[i] = *(const short8*)(Bls + (n_off + i * 16 + col) * 32 + swq);
        #pragma unroll
        for (int mb = 0; mb < 4; ++mb)
            #pragma unroll
            for (int nb = 0; nb < 2; ++nb)
                acc[mb][nb] = __builtin_amdgcn_mfma_f32_16x16x32_bf16(
                    af[mb], bf[nb], acc[mb][nb], 0, 0, 0);
    }
    int sel = blockIdx.y >> 4;                 // 0=Q 1=K 2=V (16 y-tiles/slab)
    #pragma unroll
    for (int nb = 0; nb < 2; ++nb) {
        int n = n0 + n_off + nb * 16 + col;
        int d10 = n & 1023;                    // index within Q/K/V slab
        int h_ = d10 >> 6, d = d10 & 63;
        if (sel == 0) {
            #pragma unroll
            for (int mb = 0; mb < 4; ++mb)
                #pragma unroll
                for (int r = 0; r < 4; ++r) {
                    int m = m0 + m_off + mb * 16 + quad * 4 + r;
                    int b_ = m >> 11, t_ = m & 2047;
                    qB[((size_t)(b_ * 16 + h_) * 2048 + t_) * 64 + d] =
                        f2bf(acc[mb][nb][r]);
                }
        } else if (sel == 1) {
            int hK = d >> 5, quadk = (d >> 3) & 3, j = d & 7;
            #pragma unroll
            for (int mb = 0; mb < 4; ++mb)
                #pragma unroll
                for (int r = 0; r < 4; ++r) {
                    int m = m0 + m_off + mb * 16 + quad * 4 + r;
                    int b_ = m >> 11, t_ = m & 2047;
                    int bh = b_ * 16 + h_;
                    kfrag[((((size_t)bh * 128 + (t_ >> 4)) * 2 + hK) * 64 +
                           quadk * 16 + (t_ & 15)) * 8 + j] = f2bf(acc[mb][nb][r]);
                }
        } else {
            int nbv = d >> 4, colv = d & 15;
            #pragma unroll
            for (int mb = 0; mb < 4; ++mb) {
                int m = m0 + m_off + mb * 16 + quad * 4;   // r=0 base, t&3=0
                int b_ = m >> 11, t_ = m & 2047;
                int bh = b_ * 16 + h_;
                half4 hv;
                hv[0] = (_Float16)acc[mb][nb][0]; hv[1] = (_Float16)acc[mb][nb][1];
                hv[2] = (_Float16)acc[mb][nb][2]; hv[3] = (_Float16)acc[mb][nb][3];
                *(half4*)(vfrag + ((((size_t)bh * 64 + (t_ >> 5)) * 4 + nbv) * 64 +
                          ((t_ >> 2) & 3) * 16 + colv) * 8 + ((t_ >> 4) & 1) * 4) = hv;
            }
        }
    }
}

// ---------------- output projection GEMM + bias ----------------
// 128x64 tile (BK=32, swizzled): grid (32,16)=512 blocks = 2/CU for overlap.
__global__ __launch_bounds__(256) void oproj(
        const unsigned short* __restrict__ A,
        const unsigned short* __restrict__ Bw,
        const float* __restrict__ bo,
        float* __restrict__ y) {
    __shared__ unsigned short Als[128 * 32];
    __shared__ unsigned short Bls[64 * 32];
    int wave = threadIdx.x >> 6;
    int lane = threadIdx.x & 63;
    int col  = lane & 15;
    int quad = lane >> 4;
    int m_off = (wave & 1) * 64;
    int n_off = (wave >> 1) * 32;
    int ldr = lane >> 2;
    int ldc = ((lane & 3) ^ ((lane >> 3) & 3)) * 8;
    int swq = (quad ^ ((col >> 1) & 3)) * 8;
    int m0 = blockIdx.x * 128;
    int n0 = blockIdx.y * 64;
    f32x4 acc[4][2] = {};
    for (int k0 = 0; k0 < 1024; k0 += 32) {
        __syncthreads();
        #pragma unroll
        for (int j = 0; j < 2; ++j) {
            int row = wave * 32 + j * 16;
            gld16(A + (size_t)(m0 + row + ldr) * 1024 + k0 + ldc, Als + row * 32);
        }
        {
            int row = wave * 16;
            gld16(Bw + (size_t)(n0 + row + ldr) * 1024 + k0 + ldc, Bls + row * 32);
        }
        __syncthreads();
        short8 af[4], bf[2];
        #pragma unroll
        for (int i = 0; i < 4; ++i)
            af[i] = *(const short8*)(Als + (m_off + i * 16 + col) * 32 + swq);
        #pragma unroll
        for (int i = 0; i < 2; ++i)
            bf[i] = *(const short8*)(Bls + (n_off + i * 16 + col) * 32 + swq);
        #pragma unroll
        for (int mb = 0; mb < 4; ++mb)
            #pragma unroll
            for (int nb = 0; nb < 2; ++nb)
                acc[mb][nb] = __builtin_amdgcn_mfma_f32_16x16x32_bf16(
                    af[mb], bf[nb], acc[mb][nb], 0, 0, 0);
    }
    #pragma unroll
    for (int nb = 0; nb < 2; ++nb) {
        int n = n0 + n_off + nb * 16 + col;
        float bias = bo[n];
        #pragma unroll
        for (int mb = 0; mb < 4; ++mb)
            #pragma unroll
            for (int r = 0; r < 4; ++r) {
                int m = m0 + m_off + mb * 16 + quad * 4 + r;
                y[(size_t)m * 1024 + n] = acc[mb][nb][r] + bias;
            }
    }
}

// ---------------- causal flash attention, KV-split-2, S^T trick ----------------
// ROUND-7 PROVEN VERSION (<=46us): grid 1024, launch_bounds(256,3) — the
// (256,4) KV-split-4 variant spilled KV double-buffers to scratch (240 MB
// writes). Do not tighten the VGPR bound on this kernel.
__global__ __launch_bounds__(256, 3) void attn(
        const unsigned short* __restrict__ qB,
        const unsigned short* __restrict__ kfrag,
        const _Float16* __restrict__ vfrag,
        unsigned short* __restrict__ aout) {
    __shared__ float O_comb[2][64][33];            // 16896 B (stride 33)
    __shared__ float L_comb[2][2][2][16];          //  1024 B [sl][parity][qb][q]
    int wave = threadIdx.x >> 6;
    int lane = threadIdx.x & 63;
    int col  = lane & 15;
    int quad = lane >> 4;
    int sl     = wave >> 1;                    // strip within block (0,1)
    int parity = wave & 1;                     // KV-block parity
    int bh   = blockIdx.x & 31;
    int pairidx = 31 - (blockIdx.x >> 5);      // reversed: longest strips first
    int strip = pairidx * 2 + sl;              // 0..63
    int q0 = strip * 32;
    const unsigned short* q = qB + (size_t)bh * 2048 * 64;
    const unsigned short* kf_base = kfrag + (size_t)bh * 128 * 2 * 512;
    const _Float16*       vf_base = vfrag + (size_t)bh * 64 * 4 * 512;

    short8 qf[2][2];
    #pragma unroll
    for (int qb = 0; qb < 2; ++qb)
        #pragma unroll
        for (int h = 0; h < 2; ++h)
            qf[qb][h] = *(const short8*)(q + (size_t)(q0 + qb * 16 + col) * 64 + h * 32 + quad * 8);

    f32x4 o[2][4] = {};
    float l[2] = {0.f, 0.f};

    struct KV { short8 kf[2][2]; half8 vv[4]; };
    KV bufA, bufB;

    auto load_half = [&](int it, int kv32, KV& b) {
        int K16 = it * 4 + kv32 * 2;
        #pragma unroll
        for (int p = 0; p < 2; ++p)
            #pragma unroll
            for (int h = 0; h < 2; ++h)
                b.kf[p][h] = *(const short8*)(kf_base +
                    (((size_t)(K16 + p) * 2 + h) * 64 + lane) * 8);
        #pragma unroll
        for (int nb = 0; nb < 4; ++nb)
            b.vv[nb] = *(const half8*)(vf_base +
                (((size_t)(it * 2 + kv32) * 4 + nb) * 64 + lane) * 8);
    };

    auto compute_half = [&](int it, int kv32, KV& b) {
        int kv0 = it * 64;
        bool diag = (kv0 + 63 > q0);
        #pragma unroll
        for (int par = 0; par < 2; ++par) {
            int kvbase = kv0 + kv32 * 32 + par * 16;
            f32x4 st[2] = {};
            #pragma unroll
            for (int qb = 0; qb < 2; ++qb) {
                st[qb] = __builtin_amdgcn_mfma_f32_16x16x32_bf16(b.kf[par][0], qf[qb][0], st[qb], 0, 0, 0);
                st[qb] = __builtin_amdgcn_mfma_f32_16x16x32_bf16(b.kf[par][1], qf[qb][1], st[qb], 0, 0, 0);
            }
            #pragma unroll
            for (int qb = 0; qb < 2; ++qb) {
                float p0 = __builtin_amdgcn_exp2f(st[qb][0]);
                float p1 = __builtin_amdgcn_exp2f(st[qb][1]);
                float p2 = __builtin_amdgcn_exp2f(st[qb][2]);
                float p3 = __builtin_amdgcn_exp2f(st[qb][3]);
                if (diag) {                       // wave-uniform branch
                    int qg  = q0 + qb * 16 + col;
                    int kvg = kvbase + quad * 4;
                    p0 = (kvg + 0 > qg) ? 0.f : p0;
                    p1 = (kvg + 1 > qg) ? 0.f : p1;
                    p2 = (kvg + 2 > qg) ? 0.f : p2;
                    p3 = (kvg + 3 > qg) ? 0.f : p3;
                }
                l[qb] += (p0 + p1) + (p2 + p3);
                union { fp16x2 h2[2]; half4 h4; } cvt;
                cvt.h2[0] = __builtin_amdgcn_cvt_pkrtz(p0, p1);
                cvt.h2[1] = __builtin_amdgcn_cvt_pkrtz(p2, p3);
                half4 pf = cvt.h4;
                #pragma unroll
                for (int nb = 0; nb < 4; ++nb) {
                    half4 vf = (par == 0)
                        ? __builtin_shufflevector(b.vv[nb], b.vv[nb], 0, 1, 2, 3)
                        : __builtin_shufflevector(b.vv[nb], b.vv[nb], 4, 5, 6, 7);
                    o[qb][nb] = __builtin_amdgcn_mfma_f32_16x16x16f16(pf, vf, o[qb][nb], 0, 0, 0);
                }
            }
        }
    };

    int n_iter = (q0 + 95) >> 6;               // ceil((q0+32)/64)
    if (parity < n_iter) load_half(parity, 0, bufA);
    for (int it = parity; it < n_iter; it += 2) {
        load_half(it, 1, bufB);                // prefetch 2nd half of this iter
        compute_half(it, 0, bufA);
        if (it + 2 < n_iter) load_half(it + 2, 0, bufA);   // prefetch next iter
        compute_half(it, 1, bufB);
    }

    // reduce l across quads (partials live per q=col in 4 quad groups)
    #pragma unroll
    for (int qb = 0; qb < 2; ++qb) {
        float lr = l[qb];
        lr += __shfl_xor(lr, 16);
        lr += __shfl_xor(lr, 32);
        l[qb] = lr;
    }
    if (quad == 0) {
        L_comb[sl][parity][0][col] = l[0];
        L_comb[sl][parity][1][col] = l[1];
    }
    if (parity == 1) {
        #pragma unroll
        for (int qb = 0; qb < 2; ++qb)
            #pragma unroll
            for (int nb = 0; nb < 4; ++nb)
                #pragma unroll
                for (int r = 0; r < 4; ++r)
                    O_comb[sl][lane][qb * 16 + nb * 4 + r] = o[qb][nb][r];
    }
    __syncthreads();
    if (parity == 0) {
        int b_ = bh >> 4, h_ = bh & 15;
        #pragma unroll
        for (int qb = 0; qb < 2; ++qb)
            #pragma unroll
            for (int r = 0; r < 4; ++r) {
                int qi = quad * 4 + r;
                float inv_l = 1.0f / (L_comb[sl][0][qb][qi] + L_comb[sl][1][qb][qi]);
                int t_ = q0 + qb * 16 + qi;
                #pragma unroll
                for (int nb = 0; nb < 4; ++nb) {
                    float ov = o[qb][nb][r] + O_comb[sl][lane][qb * 16 + nb * 4 + r];
                    aout[(size_t)(b_ * 2048 + t_) * 1024 + h_ * 64 + nb * 16 + col] =
                        f2bf(ov * inv_l);
                }
            }
    }
}

extern "C" void kernel_launch(void* const* d_in, const int* in_sizes, int n_in,
                              void* d_out, int out_size, void* d_ws, size_t ws_size,
                              hipStream_t stream) {
    const float* x  = (const float*)d_in[0];
    const float* Wq = (const float*)d_in[1];
    const float* Wk = (const float*)d_in[2];
    const float* Wv = (const float*)d_in[3];
    const float* Wo = (const float*)d_in[4];
    const float* bo = (const float*)d_in[5];
    float* y = (float*)d_out;

    unsigned short* xb    = (unsigned short*)d_ws;    // 4096*1024
    unsigned short* Wt    = xb    + 4194304;          // 3072*1024
    unsigned short* Wob   = Wt    + 3145728;          // 1024*1024
    unsigned short* qBb   = Wob   + 1048576;          // 32*2048*64
    unsigned short* kfr   = qBb   + 4194304;          // 32*128*2*512
    unsigned short* vfr   = kfr   + 4194304;          // 32*64*4*512 (f16)
    unsigned short* aout  = vfr   + 4194304;          // 4096*1024

    cvt_bf16<<<4096, 256, 0, stream>>>(x,  xb,  1048576);
    cvt_bf16<<<1024, 256, 0, stream>>>(Wo, Wob, 262144);
    transpose_w<<<768, 256, 0, stream>>>(Wq, Wk, Wv, Wt);
    qkv_gemm<<<dim3(32, 48), 256, 0, stream>>>(xb, Wt, qBb, kfr, (_Float16*)vfr);
    attn<<<1024, 256, 0, stream>>>(qBb, kfr, (const _Float16*)vfr, aout);
    oproj<<<dim3(32, 16), 256, 0, stream>>>(aout, Wob, bo, y);
}

// Round 12
// 170.435 us; speedup vs baseline: 1.0510x; 1.0510x over previous
//
#include <hip/hip_runtime.h>
#include <hip/hip_bf16.h>

// MHA forward, MI355X gfx950. bf16 MFMA internal compute, fp32 accumulate.
// Shapes: B=2, T=2048, C=1024, H=16, dk=64.

using short8 = __attribute__((ext_vector_type(8))) short;  // 8 bf16 (4 VGPRs)
using f32x4  = __attribute__((ext_vector_type(4))) float;  // 4 fp32 acc
using fp16x2 = __attribute__((ext_vector_type(2))) __fp16; // cvt_pkrtz result
using half4  = __attribute__((ext_vector_type(4))) _Float16;
using half8  = __attribute__((ext_vector_type(8))) _Float16;

#define SCALE_LOG2E 0.18033688011112042f   // 0.125 * log2(e), folded into Wq

__device__ __forceinline__ unsigned short f2bf(float f) {
    union { float f; unsigned u; } v; v.f = f;
    unsigned r = v.u + 0x7fffu + ((v.u >> 16) & 1u);   // RNE
    return (unsigned short)(r >> 16);
}

// async global->LDS, 16B per lane (CK-style uintptr cast)
__device__ __forceinline__ void gld16(const unsigned short* gp, unsigned short* lp) {
    __builtin_amdgcn_global_load_lds(
        (const __attribute__((address_space(1))) void*)(gp),
        (__attribute__((address_space(3))) void*)(unsigned int)(unsigned long long)(lp),
        16, 0, 0);
}

// ---------------- prep: fp32 -> bf16 elementwise (x) ----------------
__global__ void cvt_bf16(const float* __restrict__ in,
                         unsigned short* __restrict__ out, int n4) {
    int i = blockIdx.x * blockDim.x + threadIdx.x;
    if (i >= n4) return;
    float4 v = ((const float4*)in)[i];
    ushort4 o;
    o.x = f2bf(v.x); o.y = f2bf(v.y); o.z = f2bf(v.z); o.w = f2bf(v.w);
    ((ushort4*)out)[i] = o;
}

// ------- prep: Wq/Wk/Wv [16][1024][64] fp32 -> B-FRAGMENT layout bf16 -------
// wfrag slot s = ((n16*32 + kq)*64 + quad*16 + col), 8 bf16 per slot:
//   element j of slot = Wt[n16*16+col][kq*32+quad*8+j], Wt[n][k]=W[k- (c)][d]
// (n = sh*64+d, k = c). Wq pre-scaled by 0.125*log2(e) for exp2 in attn.
__global__ void transpose_w(const float* __restrict__ Wq,
                            const float* __restrict__ Wk,
                            const float* __restrict__ Wv,
                            unsigned short* __restrict__ wfrag) {
    __shared__ float tile[64][65];            // +1 pad: no bank conflicts
    int b = blockIdx.x;                        // 0..767
    int cchunk = b & 15;                       // c0 = cchunk*64
    int h = (b >> 4) & 15;
    int s = b >> 8;                            // 0=q 1=k 2=v
    const float* W = (s == 0) ? Wq : ((s == 1) ? Wk : Wv);
    float sc = (s == 0) ? SCALE_LOG2E : 1.0f;
    const float* src = W + (h * 1024 + cchunk * 64) * 64;   // [64 c][64 d]
    int t = threadIdx.x;
    #pragma unroll
    for (int it = 0; it < 4; ++it) {
        int idx = (it * 256 + t) * 4;          // 0..4095 step 4
        int cc = idx >> 6, kk = idx & 63;
        float4 v = *(const float4*)(src + idx);
        tile[cc][kk + 0] = v.x; tile[cc][kk + 1] = v.y;
        tile[cc][kk + 2] = v.z; tile[cc][kk + 3] = v.w;
    }
    __syncthreads();
    int sh = s * 16 + h;
    #pragma unroll
    for (int p = 0; p < 2; ++p) {
        int slot = p * 256 + t;                // 0..511 = 64 d x 8 cc8
        int d   = slot & 63;
        int cc8 = slot >> 6;                   // k-chunk of 8 within 64
        int n16  = sh * 4 + (d >> 4);
        int col  = d & 15;
        int kq   = cchunk * 2 + (cc8 >> 2);
        int quad = cc8 & 3;
        ushort4 lo, hi;
        lo.x = f2bf(tile[cc8 * 8 + 0][d] * sc); lo.y = f2bf(tile[cc8 * 8 + 1][d] * sc);
        lo.z = f2bf(tile[cc8 * 8 + 2][d] * sc); lo.w = f2bf(tile[cc8 * 8 + 3][d] * sc);
        hi.x = f2bf(tile[cc8 * 8 + 4][d] * sc); hi.y = f2bf(tile[cc8 * 8 + 5][d] * sc);
        hi.z = f2bf(tile[cc8 * 8 + 6][d] * sc); hi.w = f2bf(tile[cc8 * 8 + 7][d] * sc);
        unsigned short* dst = wfrag + ((size_t)((n16 * 32 + kq) * 64 + quad * 16 + col)) * 8;
        *(ushort4*)dst = lo;
        *(ushort4*)(dst + 4) = hi;
    }
}

// ------- prep: Wo [1024 n][1024 k] fp32 -> B-fragment layout bf16 -------
__global__ void wo_frag(const float* __restrict__ Wo,
                        unsigned short* __restrict__ wofrag) {
    int g = blockIdx.x * 256 + threadIdx.x;    // 0..131071 slots
    int col  = g & 15;
    int quad = (g >> 4) & 3;
    int kq   = (g >> 6) & 31;
    int n16  = g >> 11;                         // 0..63
    const float* src = Wo + (size_t)(n16 * 16 + col) * 1024 + kq * 32 + quad * 8;
    float4 a = *(const float4*)src;
    float4 b = *(const float4*)(src + 4);
    ushort4 lo, hi;
    lo.x = f2bf(a.x); lo.y = f2bf(a.y); lo.z = f2bf(a.z); lo.w = f2bf(a.w);
    hi.x = f2bf(b.x); hi.y = f2bf(b.y); hi.z = f2bf(b.z); hi.w = f2bf(b.w);
    *(ushort4*)(wofrag + (size_t)g * 8)     = lo;
    *(ushort4*)(wofrag + (size_t)g * 8 + 4) = hi;
}

// ---------------- QKV projection GEMM: A via LDS, B direct from L2 ----------------
// Block = 2 waves (128 thr), tile 64(M) x 128(N); each wave 64x64, acc[4][4].
// Grid (64,24) = 1536 blocks = 6/CU. LDS = A only (4 KB) -> ~3x less LDS
// traffic than dual-staging (the measured per-CU bottleneck at ~45us).
// B-frags: single coalesced 1KB loads from pre-fragmented wfrag (L2-resident).
__global__ __launch_bounds__(128, 4) void qkv_gemm(
        const unsigned short* __restrict__ xb,
        const unsigned short* __restrict__ wtf,
        unsigned short* __restrict__ qB,
        unsigned short* __restrict__ kfrag,
        _Float16* __restrict__ vfrag) {
    __shared__ unsigned short Als[64 * 32];
    int wave = threadIdx.x >> 6;
    int lane = threadIdx.x & 63;
    int col  = lane & 15;
    int quad = lane >> 4;
    int ldr = lane >> 2;
    int ldc = ((lane & 3) ^ ((lane >> 3) & 3)) * 8;
    int swq = (quad ^ ((col >> 1) & 3)) * 8;
    int m0 = blockIdx.x * 64;
    int n0 = blockIdx.y * 128 + wave * 64;
    int n16b = n0 >> 4;
    f32x4 acc[4][4] = {};
    for (int k0 = 0; k0 < 1024; k0 += 32) {
        int kq = k0 >> 5;
        __syncthreads();
        // B-frags direct (issued early; latency overlaps A staging)
        short8 bf[4];
        #pragma unroll
        for (int nb = 0; nb < 4; ++nb)
            bf[nb] = *(const short8*)(wtf +
                ((size_t)((n16b + nb) * 32 + kq) * 64 + lane) * 8);
        // stage shared 64-row A chunk (each wave stages 32 rows)
        #pragma unroll
        for (int j = 0; j < 2; ++j) {
            int row = wave * 32 + j * 16;
            gld16(xb + (size_t)(m0 + row + ldr) * 1024 + k0 + ldc, Als + row * 32);
        }
        __syncthreads();
        short8 af[4];
        #pragma unroll
        for (int i = 0; i < 4; ++i)
            af[i] = *(const short8*)(Als + (i * 16 + col) * 32 + swq);
        #pragma unroll
        for (int mb = 0; mb < 4; ++mb)
            #pragma unroll
            for (int nb = 0; nb < 4; ++nb)
                acc[mb][nb] = __builtin_amdgcn_mfma_f32_16x16x32_bf16(
                    af[mb], bf[nb], acc[mb][nb], 0, 0, 0);
    }
    int sel = blockIdx.y >> 3;                 // 0=Q 1=K 2=V (8 y-blocks/slab)
    #pragma unroll
    for (int nb = 0; nb < 4; ++nb) {
        int n = n0 + nb * 16 + col;
        int d10 = n & 1023;
        int h_ = d10 >> 6, d = d10 & 63;
        if (sel == 0) {
            #pragma unroll
            for (int mb = 0; mb < 4; ++mb)
                #pragma unroll
                for (int r = 0; r < 4; ++r) {
                    int m = m0 + mb * 16 + quad * 4 + r;
                    int b_ = m >> 11, t_ = m & 2047;
                    qB[((size_t)(b_ * 16 + h_) * 2048 + t_) * 64 + d] =
                        f2bf(acc[mb][nb][r]);
                }
        } else if (sel == 1) {
            int hK = d >> 5, quadk = (d >> 3) & 3, j = d & 7;
            #pragma unroll
            for (int mb = 0; mb < 4; ++mb)
                #pragma unroll
                for (int r = 0; r < 4; ++r) {
                    int m = m0 + mb * 16 + quad * 4 + r;
                    int b_ = m >> 11, t_ = m & 2047;
                    int bh = b_ * 16 + h_;
                    kfrag[((((size_t)bh * 128 + (t_ >> 4)) * 2 + hK) * 64 +
                           quadk * 16 + (t_ & 15)) * 8 + j] = f2bf(acc[mb][nb][r]);
                }
        } else {
            int nbv = d >> 4, colv = d & 15;
            #pragma unroll
            for (int mb = 0; mb < 4; ++mb) {
                int m = m0 + mb * 16 + quad * 4;           // r=0 base, t&3=0
                int b_ = m >> 11, t_ = m & 2047;
                int bh = b_ * 16 + h_;
                half4 hv;
                hv[0] = (_Float16)acc[mb][nb][0]; hv[1] = (_Float16)acc[mb][nb][1];
                hv[2] = (_Float16)acc[mb][nb][2]; hv[3] = (_Float16)acc[mb][nb][3];
                *(half4*)(vfrag + ((((size_t)bh * 64 + (t_ >> 5)) * 4 + nbv) * 64 +
                          ((t_ >> 2) & 3) * 16 + colv) * 8 + ((t_ >> 4) & 1) * 4) = hv;
            }
        }
    }
}

// ---------------- output projection GEMM + bias: A via LDS, B direct ----------------
// Block = 2 waves, tile 32(M) x 128(N); grid (128,8) = 1024 blocks = 4/CU.
__global__ __launch_bounds__(128, 4) void oproj(
        const unsigned short* __restrict__ A,
        const unsigned short* __restrict__ wof,
        const float* __restrict__ bo,
        float* __restrict__ y) {
    __shared__ unsigned short Als[32 * 32];
    int wave = threadIdx.x >> 6;
    int lane = threadIdx.x & 63;
    int col  = lane & 15;
    int quad = lane >> 4;
    int ldr = lane >> 2;
    int ldc = ((lane & 3) ^ ((lane >> 3) & 3)) * 8;
    int swq = (quad ^ ((col >> 1) & 3)) * 8;
    int m0 = blockIdx.x * 32;
    int n0 = blockIdx.y * 128 + wave * 64;
    int n16b = n0 >> 4;
    f32x4 acc[2][4] = {};
    for (int k0 = 0; k0 < 1024; k0 += 32) {
        int kq = k0 >> 5;
        __syncthreads();
        short8 bf[4];
        #pragma unroll
        for (int nb = 0; nb < 4; ++nb)
            bf[nb] = *(const short8*)(wof +
                ((size_t)((n16b + nb) * 32 + kq) * 64 + lane) * 8);
        gld16(A + (size_t)(m0 + wave * 16 + ldr) * 1024 + k0 + ldc,
              Als + (wave * 16) * 32);
        __syncthreads();
        short8 af[2];
        #pragma unroll
        for (int i = 0; i < 2; ++i)
            af[i] = *(const short8*)(Als + (i * 16 + col) * 32 + swq);
        #pragma unroll
        for (int mb = 0; mb < 2; ++mb)
            #pragma unroll
            for (int nb = 0; nb < 4; ++nb)
                acc[mb][nb] = __builtin_amdgcn_mfma_f32_16x16x32_bf16(
                    af[mb], bf[nb], acc[mb][nb], 0, 0, 0);
    }
    #pragma unroll
    for (int nb = 0; nb < 4; ++nb) {
        int n = n0 + nb * 16 + col;
        float bias = bo[n];
        #pragma unroll
        for (int mb = 0; mb < 2; ++mb)
            #pragma unroll
            for (int r = 0; r < 4; ++r) {
                int m = m0 + mb * 16 + quad * 4 + r;
                y[(size_t)m * 1024 + n] = acc[mb][nb][r] + bias;
            }
    }
}

// ---------------- causal flash attention, KV-split-2, S^T trick ----------------
// PROVEN VERSION (~45us): grid 1024, launch_bounds(256,3) — (256,4) spills
// the KV double-buffers to scratch. Do not tighten the VGPR bound.
__global__ __launch_bounds__(256, 3) void attn(
        const unsigned short* __restrict__ qB,
        const unsigned short* __restrict__ kfrag,
        const _Float16* __restrict__ vfrag,
        unsigned short* __restrict__ aout) {
    __shared__ float O_comb[2][64][33];            // 16896 B (stride 33)
    __shared__ float L_comb[2][2][2][16];          //  1024 B [sl][parity][qb][q]
    int wave = threadIdx.x >> 6;
    int lane = threadIdx.x & 63;
    int col  = lane & 15;
    int quad = lane >> 4;
    int sl     = wave >> 1;                    // strip within block (0,1)
    int parity = wave & 1;                     // KV-block parity
    int bh   = blockIdx.x & 31;
    int pairidx = 31 - (blockIdx.x >> 5);      // reversed: longest strips first
    int strip = pairidx * 2 + sl;              // 0..63
    int q0 = strip * 32;
    const unsigned short* q = qB + (size_t)bh * 2048 * 64;
    const unsigned short* kf_base = kfrag + (size_t)bh * 128 * 2 * 512;
    const _Float16*       vf_base = vfrag + (size_t)bh * 64 * 4 * 512;

    short8 qf[2][2];
    #pragma unroll
    for (int qb = 0; qb < 2; ++qb)
        #pragma unroll
        for (int h = 0; h < 2; ++h)
            qf[qb][h] = *(const short8*)(q + (size_t)(q0 + qb * 16 + col) * 64 + h * 32 + quad * 8);

    f32x4 o[2][4] = {};
    float l[2] = {0.f, 0.f};

    struct KV { short8 kf[2][2]; half8 vv[4]; };
    KV bufA, bufB;

    auto load_half = [&](int it, int kv32, KV& b) {
        int K16 = it * 4 + kv32 * 2;
        #pragma unroll
        for (int p = 0; p < 2; ++p)
            #pragma unroll
            for (int h = 0; h < 2; ++h)
                b.kf[p][h] = *(const short8*)(kf_base +
                    (((size_t)(K16 + p) * 2 + h) * 64 + lane) * 8);
        #pragma unroll
        for (int nb = 0; nb < 4; ++nb)
            b.vv[nb] = *(const half8*)(vf_base +
                (((size_t)(it * 2 + kv32) * 4 + nb) * 64 + lane) * 8);
    };

    auto compute_half = [&](int it, int kv32, KV& b) {
        int kv0 = it * 64;
        bool diag = (kv0 + 63 > q0);
        #pragma unroll
        for (int par = 0; par < 2; ++par) {
            int kvbase = kv0 + kv32 * 32 + par * 16;
            f32x4 st[2] = {};
            #pragma unroll
            for (int qb = 0; qb < 2; ++qb) {
                st[qb] = __builtin_amdgcn_mfma_f32_16x16x32_bf16(b.kf[par][0], qf[qb][0], st[qb], 0, 0, 0);
                st[qb] = __builtin_amdgcn_mfma_f32_16x16x32_bf16(b.kf[par][1], qf[qb][1], st[qb], 0, 0, 0);
            }
            #pragma unroll
            for (int qb = 0; qb < 2; ++qb) {
                float p0 = __builtin_amdgcn_exp2f(st[qb][0]);
                float p1 = __builtin_amdgcn_exp2f(st[qb][1]);
                float p2 = __builtin_amdgcn_exp2f(st[qb][2]);
                float p3 = __builtin_amdgcn_exp2f(st[qb][3]);
                if (diag) {                       // wave-uniform branch
                    int qg  = q0 + qb * 16 + col;
                    int kvg = kvbase + quad * 4;
                    p0 = (kvg + 0 > qg) ? 0.f : p0;
                    p1 = (kvg + 1 > qg) ? 0.f : p1;
                    p2 = (kvg + 2 > qg) ? 0.f : p2;
                    p3 = (kvg + 3 > qg) ? 0.f : p3;
                }
                l[qb] += (p0 + p1) + (p2 + p3);
                union { fp16x2 h2[2]; half4 h4; } cvt;
                cvt.h2[0] = __builtin_amdgcn_cvt_pkrtz(p0, p1);
                cvt.h2[1] = __builtin_amdgcn_cvt_pkrtz(p2, p3);
                half4 pf = cvt.h4;
                #pragma unroll
                for (int nb = 0; nb < 4; ++nb) {
                    half4 vf = (par == 0)
                        ? __builtin_shufflevector(b.vv[nb], b.vv[nb], 0, 1, 2, 3)
                        : __builtin_shufflevector(b.vv[nb], b.vv[nb], 4, 5, 6, 7);
                    o[qb][nb] = __builtin_amdgcn_mfma_f32_16x16x16f16(pf, vf, o[qb][nb], 0, 0, 0);
                }
            }
        }
    };

    int n_iter = (q0 + 95) >> 6;               // ceil((q0+32)/64)
    if (parity < n_iter) load_half(parity, 0, bufA);
    for (int it = parity; it < n_iter; it += 2) {
        load_half(it, 1, bufB);                // prefetch 2nd half of this iter
        compute_half(it, 0, bufA);
        if (it + 2 < n_iter) load_half(it + 2, 0, bufA);   // prefetch next iter
        compute_half(it, 1, bufB);
    }

    // reduce l across quads (partials live per q=col in 4 quad groups)
    #pragma unroll
    for (int qb = 0; qb < 2; ++qb) {
        float lr = l[qb];
        lr += __shfl_xor(lr, 16);
        lr += __shfl_xor(lr, 32);
        l[qb] = lr;
    }
    if (quad == 0) {
        L_comb[sl][parity][0][col] = l[0];
        L_comb[sl][parity][1][col] = l[1];
    }
    if (parity == 1) {
        #pragma unroll
        for (int qb = 0; qb < 2; ++qb)
            #pragma unroll
            for (int nb = 0; nb < 4; ++nb)
                #pragma unroll
                for (int r = 0; r < 4; ++r)
                    O_comb[sl][lane][qb * 16 + nb * 4 + r] = o[qb][nb][r];
    }
    __syncthreads();
    if (parity == 0) {
        int b_ = bh >> 4, h_ = bh & 15;
        #pragma unroll
        for (int qb = 0; qb < 2; ++qb)
            #pragma unroll
            for (int r = 0; r < 4; ++r) {
                int qi = quad * 4 + r;
                float inv_l = 1.0f / (L_comb[sl][0][qb][qi] + L_comb[sl][1][qb][qi]);
                int t_ = q0 + qb * 16 + qi;
                #pragma unroll
                for (int nb = 0; nb < 4; ++nb) {
                    float ov = o[qb][nb][r] + O_comb[sl][lane][qb * 16 + nb * 4 + r];
                    aout[(size_t)(b_ * 2048 + t_) * 1024 + h_ * 64 + nb * 16 + col] =
                        f2bf(ov * inv_l);
                }
            }
    }
}

extern "C" void kernel_launch(void* const* d_in, const int* in_sizes, int n_in,
                              void* d_out, int out_size, void* d_ws, size_t ws_size,
                              hipStream_t stream) {
    const float* x  = (const float*)d_in[0];
    const float* Wq = (const float*)d_in[1];
    const float* Wk = (const float*)d_in[2];
    const float* Wv = (const float*)d_in[3];
    const float* Wo = (const float*)d_in[4];
    const float* bo = (const float*)d_in[5];
    float* y = (float*)d_out;

    unsigned short* xb    = (unsigned short*)d_ws;    // 4096*1024
    unsigned short* Wtf   = xb    + 4194304;          // 3072*1024 (B-frag layout)
    unsigned short* Wof   = Wtf   + 3145728;          // 1024*1024 (B-frag layout)
    unsigned short* qBb   = Wof   + 1048576;          // 32*2048*64
    unsigned short* kfr   = qBb   + 4194304;          // 32*128*2*512
    unsigned short* vfr   = kfr   + 4194304;          // 32*64*4*512 (f16)
    unsigned short* aout  = vfr   + 4194304;          // 4096*1024

    cvt_bf16<<<4096, 256, 0, stream>>>(x, xb, 1048576);
    transpose_w<<<768, 256, 0, stream>>>(Wq, Wk, Wv, Wtf);
    wo_frag<<<512, 256, 0, stream>>>(Wo, Wof);
    qkv_gemm<<<dim3(64, 24), 128, 0, stream>>>(xb, Wtf, qBb, kfr, (_Float16*)vfr);
    attn<<<1024, 256, 0, stream>>>(qBb, kfr, (const _Float16*)vfr, aout);
    oproj<<<dim3(128, 8), 128, 0, stream>>>(aout, Wof, bo, y);
}